// Round 9
// baseline (83.496 us; speedup 1.0000x reference)
//
#include <hip/hip_runtime.h>
#include <hip/hip_bf16.h>

// Problem constants (fixed by setup_inputs)
#define NB    16
#define NC    1024
#define NF    4096
#define NFINE (NB*NF)     // 65536
#define CIN   256
#define CSKIP 128
#define KH    (CIN+CSKIP) // 384
#define CMID  256
#define COUT  256

typedef __attribute__((ext_vector_type(8))) short short8;
typedef __attribute__((ext_vector_type(4))) float f32x4;
typedef __attribute__((ext_vector_type(4))) unsigned int u32x4;

// ---------------- K0: bin coarse points into 8^3 grid (counting sort) ----------------
__global__ __launch_bounds__(256)
void bin_kernel(const float* __restrict__ pos,
                float* __restrict__ gp,          // [NB*NC*4]: {x,y,z,idx}
                int* __restrict__ gcs)           // [NB*513]
{
    __shared__ int cnt[512];
    __shared__ float lx[NC], ly[NC], lz[NC];
    __shared__ short lcell[NC];
    const int b = blockIdx.x, t = threadIdx.x;
    for (int i = t; i < 512; i += 256) cnt[i] = 0;
    __syncthreads();
    const float* pc = pos + (size_t)b*NC*3;
    #pragma unroll
    for (int u = 0; u < 4; ++u) {
        int i = t + u*256;
        float x = pc[3*i+0], y = pc[3*i+1], z = pc[3*i+2];
        int cx = min(7, (int)(x*8.0f));
        int cy = min(7, (int)(y*8.0f));
        int cz = min(7, (int)(z*8.0f));
        int c = (cz*8 + cy)*8 + cx;
        lx[i] = x; ly[i] = y; lz[i] = z; lcell[i] = (short)c;
        atomicAdd(&cnt[c], 1);
    }
    __syncthreads();
    if (t < 64) {
        int v[8]; int s = 0;
        #pragma unroll
        for (int u = 0; u < 8; ++u) { v[u] = cnt[t*8+u]; s += v[u]; }
        int pfx = s;
        #pragma unroll
        for (int m = 1; m < 64; m <<= 1) {
            int o = __shfl_up(pfx, m);
            if (t >= m) pfx += o;
        }
        pfx -= s;
        #pragma unroll
        for (int u = 0; u < 8; ++u) {
            gcs[b*513 + t*8+u] = pfx;
            cnt[t*8+u] = pfx;
            pfx += v[u];
        }
        if (t == 63) gcs[b*513 + 512] = NC;
    }
    __syncthreads();
    #pragma unroll
    for (int u = 0; u < 4; ++u) {
        int i = t + u*256;
        int c = lcell[i];
        int dst = atomicAdd(&cnt[c], 1);
        f32x4 v; v[0] = lx[i]; v[1] = ly[i]; v[2] = lz[i]; v[3] = __int_as_float(i);
        *(f32x4*)&gp[(size_t)(b*NC + dst)*4] = v;
    }
}

// ---------------- K1: exact 3-NN via grid, 8 lanes/query ----------------
#define KQPB 64   // queries per 512-thread block -> 1024 blocks, 4 blocks/CU

#define INS(d, j) do {                                        \
    bool c2 = (d) < dB, c1 = (d) < dA, c0 = (d) < d0;         \
    dB = c1 ? dA : (c2 ? (d) : dB);                           \
    iB = c1 ? iA : (c2 ? (j) : iB);                           \
    dA = c0 ? d0 : (c1 ? (d) : dA);                           \
    iA = c0 ? i0 : (c1 ? (j) : iA);                           \
    d0 = c0 ? (d) : d0;                                       \
    i0 = c0 ? (j) : i0;                                       \
} while (0)

#define SCAN(JS, JE) for (int j = (JS) + g; j < (JE); j += 8) {        \
    const f32x4 p = *(const f32x4*)&pp[j][0];                          \
    float fx = qx - p[0], fy = qy - p[1], fz = qz - p[2];              \
    float dd = fx*fx + fy*fy + fz*fz;                                  \
    INS(dd, j);                                                        \
}

#define MERGE8() do {                                                          \
    _Pragma("unroll")                                                          \
    for (int mm = 1; mm < 8; mm <<= 1) {                                       \
        float e0 = __shfl_xor(d0, mm), e1 = __shfl_xor(dA, mm), e2 = __shfl_xor(dB, mm); \
        int   f0 = __shfl_xor(i0, mm), f1 = __shfl_xor(iA, mm), f2 = __shfl_xor(iB, mm); \
        INS(e0, f0); INS(e1, f1); INS(e2, f2);                                 \
    }                                                                          \
} while (0)

__global__ __launch_bounds__(512)
void knn_grid_kernel(const float* __restrict__ pos_skip,
                     const float* __restrict__ gp,
                     const int* __restrict__ gcs,
                     int* __restrict__ widx, float* __restrict__ wval)
{
    __shared__ __align__(16) float pp[NC][4];       // 16KB
    __shared__ unsigned short cs[513];
    const int bpc = NF/KQPB;              // 64 blocks per cloud
    const int b  = blockIdx.x / bpc;
    const int qb = blockIdx.x % bpc;
    const int t  = threadIdx.x;
    for (int i = t; i < NC; i += 512)
        *(f32x4*)&pp[i][0] = *(const f32x4*)&gp[(size_t)(b*NC + i)*4];
    for (int i = t; i < 513; i += 512) cs[i] = (unsigned short)gcs[b*513 + i];
    __syncthreads();

    const int g  = t & 7;
    const int ql = t >> 3;                // 0..63
    const int q  = b*NF + qb*KQPB + ql;
    const float qx = pos_skip[(size_t)q*3+0];
    const float qy = pos_skip[(size_t)q*3+1];
    const float qz = pos_skip[(size_t)q*3+2];
    const int cx = min(7, (int)(qx*8.0f));
    const int cy = min(7, (int)(qy*8.0f));
    const int cz = min(7, (int)(qz*8.0f));

    float d0 = 3.0e38f, dA = 3.0e38f, dB = 3.0e38f;
    int   i0 = 0,       iA = 0,       iB = 0;

    const int xlo = max(cx-1,0), xhi = min(cx+1,7);
    const int ylo = max(cy-1,0), yhi = min(cy+1,7);
    const int zlo = max(cz-1,0), zhi = min(cz+1,7);
    #pragma unroll
    for (int r = 0; r < 9; ++r) {
        const int z = cz - 1 + r/3;
        const int y = cy - 1 + r%3;
        const bool ok = ((unsigned)z < 8u) & ((unsigned)y < 8u);
        const int rb = (z*8 + y)*8;
        int js = 0, je = 0;
        if (ok) { js = cs[rb + xlo]; je = cs[rb + xhi + 1]; }
        SCAN(js, je);
    }
    MERGE8();

    float m1 = 3.0e38f;
    if (xlo > 0) m1 = fminf(m1, qx - xlo*0.125f);
    if (xhi < 7) m1 = fminf(m1, (xhi+1)*0.125f - qx);
    if (ylo > 0) m1 = fminf(m1, qy - ylo*0.125f);
    if (yhi < 7) m1 = fminf(m1, (yhi+1)*0.125f - qy);
    if (zlo > 0) m1 = fminf(m1, qz - zlo*0.125f);
    if (zhi < 7) m1 = fminf(m1, (zhi+1)*0.125f - qz);

    if (dB > m1*m1) {
        const float s0 = d0, s1 = dA, s2 = dB;
        const int   t0 = i0, t1 = iA, t2 = iB;
        d0 = dA = dB = 3.0e38f; i0 = iA = iB = 0;

        const int xlo2 = max(cx-2,0), xhi2 = min(cx+2,7);
        const int ylo2 = max(cy-2,0), yhi2 = min(cy+2,7);
        const int zlo2 = max(cz-2,0), zhi2 = min(cz+2,7);
        for (int z = zlo2; z <= zhi2; ++z)
        for (int y = ylo2; y <= yhi2; ++y) {
            const int rb = (z*8 + y)*8;
            const bool inner_zy = (z >= zlo && z <= zhi && y >= ylo && y <= yhi);
            int jsA, jeA, jsB, jeB;
            if (inner_zy) {
                jsA = cs[rb + xlo2]; jeA = cs[rb + xlo];
                jsB = cs[rb + xhi + 1]; jeB = cs[rb + xhi2 + 1];
            } else {
                jsA = cs[rb + xlo2]; jeA = cs[rb + xhi2 + 1];
                jsB = 0; jeB = 0;
            }
            SCAN(jsA, jeA);
            SCAN(jsB, jeB);
        }
        MERGE8();
        INS(s0, t0); INS(s1, t1); INS(s2, t2);

        float m2 = 3.0e38f;
        if (xlo2 > 0) m2 = fminf(m2, qx - xlo2*0.125f);
        if (xhi2 < 7) m2 = fminf(m2, (xhi2+1)*0.125f - qx);
        if (ylo2 > 0) m2 = fminf(m2, qy - ylo2*0.125f);
        if (yhi2 < 7) m2 = fminf(m2, (yhi2+1)*0.125f - qy);
        if (zlo2 > 0) m2 = fminf(m2, qz - zlo2*0.125f);
        if (zhi2 < 7) m2 = fminf(m2, (zhi2+1)*0.125f - qz);
        if (dB > m2*m2) {
            const float u0 = d0, u1 = dA, u2 = dB;
            const int   v0 = i0, v1 = iA, v2 = iB;
            d0 = dA = dB = 3.0e38f; i0 = iA = iB = 0;
            for (int j = g; j < NC; j += 8) {
                const f32x4 p = *(const f32x4*)&pp[j][0];
                int pcx = min(7, (int)(p[0]*8.0f));
                int pcy = min(7, (int)(p[1]*8.0f));
                int pcz = min(7, (int)(p[2]*8.0f));
                if (pcx >= xlo2 && pcx <= xhi2 && pcy >= ylo2 && pcy <= yhi2 &&
                    pcz >= zlo2 && pcz <= zhi2) continue;
                float fx = qx - p[0], fy = qy - p[1], fz = qz - p[2];
                float dd = fx*fx + fy*fy + fz*fz;
                INS(dd, j);
            }
            MERGE8();
            INS(u0, v0); INS(u1, v1); INS(u2, v2);
        }
    }

    if (g == 0) {
        const int o0 = __float_as_int(pp[i0][3]);
        const int o1 = __float_as_int(pp[iA][3]);
        const int o2 = __float_as_int(pp[iB][3]);
        float w0 = 1.0f / fmaxf(d0, 1e-16f);
        float w1 = 1.0f / fmaxf(dA, 1e-16f);
        float w2 = 1.0f / fmaxf(dB, 1e-16f);
        float inv = 1.0f / (w0 + w1 + w2);
        widx[q*3+0] = b*NC + o0;  wval[q*3+0] = w0*inv;
        widx[q*3+1] = b*NC + o1;  wval[q*3+1] = w1*inv;
        widx[q*3+2] = b*NC + o2;  wval[q*3+2] = w2*inv;
    }
}

// ---------------- K2: weights -> bf16, transposed [N][K] ----------------
__global__ __launch_bounds__(256)
void prep_weights(const float* __restrict__ W1, const float* __restrict__ W2,
                  __hip_bfloat16* __restrict__ W1t, __hip_bfloat16* __restrict__ W2t)
{
    int e = blockIdx.x*256 + threadIdx.x;
    if (e < CMID*KH) {
        int n = e / KH, k = e % KH;
        W1t[e] = __float2bfloat16(W1[(size_t)k*CMID + n]);
    }
    int e2 = e - CMID*KH;
    if (e2 >= 0 && e2 < COUT*CMID) {
        int n = e2 / CMID, k = e2 % CMID;
        W2t[e2] = __float2bfloat16(W2[(size_t)k*COUT + n]);
    }
}

// ---------------- fused MLP, 2-deep prefetch ----------------
// BM=64, BN=256, BK=64; 8 waves (2x4), wave tile 32x64.
// Global loads for step S+2 issued during step S's MFMA (~2 steps of latency cover).
__global__ __launch_bounds__(512, 2)
void mlp_fused(const float* __restrict__ x,
               const float* __restrict__ x_skip,
               const int* __restrict__ widx,
               const float* __restrict__ wval,
               const __hip_bfloat16* __restrict__ W1t,   // [CMID][KH]
               const float* __restrict__ b1,
               const __hip_bfloat16* __restrict__ W2t,   // [COUT][CMID]
               const float* __restrict__ b2,
               float* __restrict__ out)
{
    __shared__ __align__(16) short As[64][64];     //  8KB
    __shared__ __align__(16) short Bs[256][64];    // 32KB
    __shared__ __align__(16) short Hs[64][256];    // 32KB
    const int nwg = gridDim.x;                     // 1024 (%8==0)
    const int tile = (blockIdx.x & 7)*(nwg >> 3) + (blockIdx.x >> 3);
    const int m0 = tile * 64;

    const int t = threadIdx.x;
    const int wave = t >> 6, lane = t & 63;
    const int wm = wave >> 2, wn = wave & 3;       // 2x4 wave grid
    const int rl = lane & 15, kq = lane >> 4;
    const short* B1r = (const short*)W1t;
    const short* B2r = (const short*)W2t;

    const int ar = t >> 3;        // A-staging row 0..63
    const int ac = t & 7;         // A chunk 0..7

    const int gr = m0 + ar;
    const int j0 = widx[gr*3+0], j1 = widx[gr*3+1], j2 = widx[gr*3+2];
    const float w0 = wval[gr*3+0], w1 = wval[gr*3+1], w2 = wval[gr*3+2];

    f32x4 rA0[6], rA1[6];
    u32x4 rB0[4], rB1[4];

    #define LOADB(RB, BP, KT, K0) do {                                         \
        _Pragma("unroll")                                                      \
        for (int i = 0; i < 4; ++i) {                                          \
            const int ch = t + i*512;                                          \
            const int rr = ch >> 3, cc = ch & 7;                               \
            RB[i] = *(const u32x4*)&(BP)[(size_t)rr*(KT) + (K0) + cc*8];       \
        }                                                                      \
    } while (0)

    // K0 is a compile-time literal at every use; branch folds.
    #define LOADA1(RA, K0) do {                                               \
        if ((K0) < CIN) {                                                      \
            const int k = (K0) + ac*8;                                         \
            const float* p0 = &x[(size_t)j0*CIN + k];                          \
            const float* p1 = &x[(size_t)j1*CIN + k];                          \
            const float* p2 = &x[(size_t)j2*CIN + k];                          \
            RA[0] = *(const f32x4*)p0; RA[1] = *(const f32x4*)(p0+4);          \
            RA[2] = *(const f32x4*)p1; RA[3] = *(const f32x4*)(p1+4);          \
            RA[4] = *(const f32x4*)p2; RA[5] = *(const f32x4*)(p2+4);          \
        } else {                                                               \
            const int k = (K0) + ac*8 - CIN;                                   \
            const float* sp = &x_skip[(size_t)gr*CSKIP + k];                   \
            RA[0] = *(const f32x4*)sp; RA[1] = *(const f32x4*)(sp+4);          \
        }                                                                      \
    } while (0)

    // single chunk per thread (fixes r8's OOB 2-chunk skip path)
    #define STAGE_A(RA, K0) do {                                               \
        short8 sv;                                                             \
        if ((K0) < CIN) {                                                      \
            _Pragma("unroll")                                                  \
            for (int u = 0; u < 2; ++u) {                                      \
                f32x4 a = RA[u], bq = RA[2+u], c = RA[4+u];                    \
                _Pragma("unroll")                                              \
                for (int e = 0; e < 4; ++e) {                                  \
                    float v = w0*a[e] + w1*bq[e] + w2*c[e];                    \
                    __hip_bfloat16 bb = __float2bfloat16(v);                   \
                    ((short*)&sv)[u*4+e] = *(short*)&bb;                       \
                }                                                              \
            }                                                                  \
        } else {                                                               \
            _Pragma("unroll")                                                  \
            for (int u = 0; u < 2; ++u) {                                      \
                f32x4 a = RA[u];                                               \
                _Pragma("unroll")                                              \
                for (int e = 0; e < 4; ++e) {                                  \
                    __hip_bfloat16 bb = __float2bfloat16(a[e]);                \
                    ((short*)&sv)[u*4+e] = *(short*)&bb;                       \
                }                                                              \
            }                                                                  \
        }                                                                      \
        *(short8*)&As[ar][(ac ^ (ar&7))*8] = sv;                               \
    } while (0)

    #define STAGE_B(RB) do {                                                   \
        _Pragma("unroll")                                                      \
        for (int i = 0; i < 4; ++i) {                                          \
            const int ch = t + i*512;                                          \
            const int rr = ch >> 3, cc = ch & 7;                               \
            *(u32x4*)&Bs[rr][(cc ^ (rr&7))*8] = RB[i];                         \
        }                                                                      \
    } while (0)

    f32x4 acc[2][4] = {};

    #define MFMA1() do {                                                       \
        _Pragma("unroll")                                                      \
        for (int kh = 0; kh < 2; ++kh) {                                       \
            const int kc = kh*4 + kq;                                          \
            short8 af[2], bf[4];                                               \
            _Pragma("unroll")                                                  \
            for (int mf = 0; mf < 2; ++mf)                                     \
                af[mf] = *(const short8*)&As[wm*32 + mf*16 + rl][(kc ^ (rl&7))*8]; \
            _Pragma("unroll")                                                  \
            for (int nf = 0; nf < 4; ++nf)                                     \
                bf[nf] = *(const short8*)&Bs[wn*64 + nf*16 + rl][(kc ^ (rl&7))*8]; \
            _Pragma("unroll")                                                  \
            for (int mf = 0; mf < 2; ++mf)                                     \
            _Pragma("unroll")                                                  \
            for (int nf = 0; nf < 4; ++nf)                                     \
                acc[mf][nf] = __builtin_amdgcn_mfma_f32_16x16x32_bf16(af[mf], bf[nf], acc[mf][nf], 0,0,0); \
        }                                                                      \
    } while (0)

    // ---- prologue: 2 steps in flight ----
    LOADA1(rA0, 0);   LOADB(rB0, B1r, KH, 0);
    LOADA1(rA1, 64);  LOADB(rB1, B1r, KH, 64);

    #define PHASE1_STEP(S, RA, RB, LOADNEXT) do {                              \
        __syncthreads();                                                       \
        STAGE_A(RA, (S)*64);                                                   \
        STAGE_B(RB);                                                           \
        __syncthreads();                                                       \
        LOADNEXT                                                               \
        MFMA1();                                                               \
    } while (0)

    PHASE1_STEP(0, rA0, rB0, { LOADA1(rA0, 128); LOADB(rB0, B1r, KH, 128); });
    PHASE1_STEP(1, rA1, rB1, { LOADA1(rA1, 192); LOADB(rB1, B1r, KH, 192); });
    PHASE1_STEP(2, rA0, rB0, { LOADA1(rA0, 256); LOADB(rB0, B1r, KH, 256); });
    PHASE1_STEP(3, rA1, rB1, { LOADA1(rA1, 320); LOADB(rB1, B1r, KH, 320); });
    PHASE1_STEP(4, rA0, rB0, { LOADB(rB0, B2r, CMID, 0);   });
    PHASE1_STEP(5, rA1, rB1, { LOADB(rB1, B2r, CMID, 64);  });

    // ---- epilogue 1: relu+bias -> Hs (bf16, chunk-XOR swizzled) ----
    #pragma unroll
    for (int mf = 0; mf < 2; ++mf)
    #pragma unroll
    for (int nf = 0; nf < 4; ++nf) {
        const int col = wn*64 + nf*16 + rl;
        const float bv = b1[col];
        #pragma unroll
        for (int i = 0; i < 4; ++i) {
            const int row = wm*32 + mf*16 + kq*4 + i;
            float v = fmaxf(acc[mf][nf][i] + bv, 0.0f);
            __hip_bfloat16 bb = __float2bfloat16(v);
            Hs[row][((col >> 3) ^ (row & 7))*8 + (col & 7)] = *(short*)&bb;
        }
    }
    __syncthreads();   // Hs complete; phase-1 Bs reads done

    // ---- phase 2: K = 256, 4 steps; A = Hs ----
    f32x4 acc2[2][4] = {};

    #define MFMA2(S2) do {                                                     \
        _Pragma("unroll")                                                      \
        for (int kh = 0; kh < 2; ++kh) {                                       \
            const int kcl = kh*4 + kq;                                         \
            const int kca = (S2)*8 + kcl;                                      \
            short8 af[2], bf[4];                                               \
            _Pragma("unroll")                                                  \
            for (int mf = 0; mf < 2; ++mf)                                     \
                af[mf] = *(const short8*)&Hs[wm*32 + mf*16 + rl][(kca ^ (rl&7))*8]; \
            _Pragma("unroll")                                                  \
            for (int nf = 0; nf < 4; ++nf)                                     \
                bf[nf] = *(const short8*)&Bs[wn*64 + nf*16 + rl][(kcl ^ (rl&7))*8]; \
            _Pragma("unroll")                                                  \
            for (int mf = 0; mf < 2; ++mf)                                     \
            _Pragma("unroll")                                                  \
            for (int nf = 0; nf < 4; ++nf)                                     \
                acc2[mf][nf] = __builtin_amdgcn_mfma_f32_16x16x32_bf16(af[mf], bf[nf], acc2[mf][nf], 0,0,0); \
        }                                                                      \
    } while (0)

    #define PHASE2_STEP(S2, RB, LOADNEXT, FIRSTBAR) do {                       \
        FIRSTBAR                                                               \
        STAGE_B(RB);                                                           \
        __syncthreads();                                                       \
        LOADNEXT                                                               \
        MFMA2(S2);                                                             \
    } while (0)

    PHASE2_STEP(0, rB0, { LOADB(rB0, B2r, CMID, 128); }, );
    PHASE2_STEP(1, rB1, { LOADB(rB1, B2r, CMID, 192); }, __syncthreads(););
    PHASE2_STEP(2, rB0, { }, __syncthreads(););
    PHASE2_STEP(3, rB1, { }, __syncthreads(););

    // ---- epilogue 2: relu+bias -> out f32 ----
    #pragma unroll
    for (int mf = 0; mf < 2; ++mf)
    #pragma unroll
    for (int nf = 0; nf < 4; ++nf) {
        const int col = wn*64 + nf*16 + rl;
        const float bv = b2[col];
        #pragma unroll
        for (int i = 0; i < 4; ++i) {
            const int row = m0 + wm*32 + mf*16 + kq*4 + i;
            out[(size_t)row*COUT + col] = fmaxf(acc2[mf][nf][i] + bv, 0.0f);
        }
    }
    #undef LOADB
    #undef LOADA1
    #undef STAGE_A
    #undef STAGE_B
    #undef MFMA1
    #undef MFMA2
    #undef PHASE1_STEP
    #undef PHASE2_STEP
}

// ---------------- K6: pos_skip + batch chunks ----------------
__global__ __launch_bounds__(256)
void tail_kernel(const float* __restrict__ pos_skip, float* __restrict__ out)
{
    int e = blockIdx.x*256 + threadIdx.x;
    if (e < NFINE*3) out[(size_t)NFINE*COUT + e] = pos_skip[e];
    if (e < NFINE)   out[(size_t)NFINE*COUT + (size_t)NFINE*3 + e] = (float)(e / NF);
}

extern "C" void kernel_launch(void* const* d_in, const int* in_sizes, int n_in,
                              void* d_out, int out_size, void* d_ws, size_t ws_size,
                              hipStream_t stream) {
    const float* x        = (const float*)d_in[0];
    const float* pos      = (const float*)d_in[1];
    const float* x_skip   = (const float*)d_in[4];
    const float* pos_skip = (const float*)d_in[5];
    const float* W1       = (const float*)d_in[8];
    const float* b1       = (const float*)d_in[9];
    const float* W2       = (const float*)d_in[10];
    const float* b2       = (const float*)d_in[11];
    float* out = (float*)d_out;
    char* ws = (char*)d_ws;

    int*            widx = (int*)  (ws + 0);                 //   786,432 B
    float*          wval = (float*)(ws + 786432);            //   786,432 B
    __hip_bfloat16* W1t  = (__hip_bfloat16*)(ws + 1572864);  //   196,608 B
    __hip_bfloat16* W2t  = (__hip_bfloat16*)(ws + 1769472);  //   131,072 B
    float*          gp   = (float*)(ws + 1900544);           //   262,144 B
    int*            gcs  = (int*)  (ws + 2162688);           //    32,832 B

    hipLaunchKernelGGL(bin_kernel, dim3(NB), dim3(256), 0, stream,
                       pos, gp, gcs);
    hipLaunchKernelGGL(knn_grid_kernel, dim3(NB*(NF/KQPB)), dim3(512), 0, stream,
                       pos_skip, gp, gcs, widx, wval);
    hipLaunchKernelGGL(prep_weights, dim3((CMID*KH + COUT*CMID + 255)/256), dim3(256), 0, stream,
                       W1, W2, W1t, W2t);
    hipLaunchKernelGGL(mlp_fused, dim3(NFINE/64), dim3(512), 0, stream,
                       x, x_skip, widx, wval, W1t, b1, W2t, b2, out);
    hipLaunchKernelGGL(tail_kernel, dim3((NFINE*3 + 255)/256), dim3(256), 0, stream,
                       pos_skip, out);
}